// Round 4
// baseline (84.863 us; speedup 1.0000x reference)
//
#include <hip/hip_runtime.h>

// Chamfer loss between subsampled point clouds.
// srcA: (64000,2) fp32 -> A = 8000 pts  (fp32 linspace trunc, matches jnp)
// srcB: (80000,2) fp32 -> B = 10000 pts
// out  = 0.5 * ( mean_i min_j |A_i - B_j| + mean_j min_i |A_i - B_j| )
//
// 3-op inner loop: d^2 = p^2 + (q^2 - 2 q.p). Columns staged in LDS as
// float4 (-2qx, -2qy, qx^2+qy^2, 0); per pair: fma, fma, fmin. p^2 is
// row-constant -> added once at partial-store time; reduce clamps >=0
// before sqrt (cancellation guard). Error budget ~1e-6 on the scalar
// output vs 1.07e-4 threshold.
//
// Grid: 1262 blocks (~4.93/CU) covering BOTH directions in one dispatch.
// Each block: 1024 rows (4/thread) x 128-column LDS chunk (broadcast
// reads, conflict-free). Partial per-(row,chunk) min direct-stored (no
// atomics, no init). Second dispatch min-reduces chunks, sqrt, mean,
// atomicAdd into d_out (zeroed by block 0 of dispatch 1, stream-ordered).

#define SRC_A 64000
#define SRC_B 80000
#define NA 8000
#define NB 10000

#define BLOCK 256
#define CHUNK 128          // columns staged in LDS per block
#define RPT 4              // rows per thread
#define RPB (BLOCK * RPT)  // 1024 rows per block

#define NB1X 8    // ceil(8000/1024)
#define NB1Y 79   // ceil(10000/128)
#define NB2X 10   // ceil(10000/1024)
#define NB2Y 63   // ceil(8000/128)
#define NBLK1 (NB1X * NB1Y)   // 632
#define NBLK2 (NB2X * NB2Y)   // 630

#define P1_STRIDE (NB1X * RPB)            // 8192
#define P2_STRIDE (NB2X * RPB)            // 10240
#define P2_OFF_FLOATS (NB1Y * P1_STRIDE)  // 647168 floats (~2.6 MB)

__global__ __launch_bounds__(BLOCK) void chamfer_partial(
        const float2* __restrict__ srcA, const float2* __restrict__ srcB,
        float* __restrict__ ws, float* __restrict__ out) {
    if (blockIdx.x == 0 && threadIdx.x == 0) *out = 0.0f;  // init for reduce's atomicAdd

    const bool pass1 = (int)blockIdx.x < NBLK1;
    const float2* srcRows; const float2* srcCols;
    float rowDelta, colDelta;
    int rowSrcMax, colSrcMax, nrows, ncols, bx, by, pstride;
    float* P;
    if (pass1) {
        int f = (int)blockIdx.x;
        bx = f % NB1X; by = f / NB1X;
        srcRows = srcA; rowDelta = (float)(SRC_A - 1) / (float)(NA - 1);
        rowSrcMax = SRC_A - 1; nrows = NA;
        srcCols = srcB; colDelta = (float)(SRC_B - 1) / (float)(NB - 1);
        colSrcMax = SRC_B - 1; ncols = NB;
        P = ws; pstride = P1_STRIDE;
    } else {
        int f = (int)blockIdx.x - NBLK1;
        bx = f % NB2X; by = f / NB2X;
        srcRows = srcB; rowDelta = (float)(SRC_B - 1) / (float)(NB - 1);
        rowSrcMax = SRC_B - 1; nrows = NB;
        srcCols = srcA; colDelta = (float)(SRC_A - 1) / (float)(NA - 1);
        colSrcMax = SRC_A - 1; ncols = NA;
        P = ws + P2_OFF_FLOATS; pstride = P2_STRIDE;
    }

    // stage column chunk as (-2qx, -2qy, qx^2+qy^2, 0)
    __shared__ float4 sc[CHUNK];
    int c0 = by * CHUNK;
    int cn = ncols - c0; if (cn > CHUNK) cn = CHUNK;
    int j = (int)threadIdx.x;
    if (j < cn) {
        int cidx = (int)((float)(c0 + j) * colDelta);
        if (cidx > colSrcMax) cidx = colSrcMax;
        float2 q = srcCols[cidx];
        sc[j] = make_float4(-2.0f * q.x, -2.0f * q.y,
                            fmaf(q.x, q.x, q.y * q.y), 0.0f);
    }
    __syncthreads();

    float2 p[RPT];
    float  p2[RPT];
    float  m[RPT];
    int r0 = bx * RPB + (int)threadIdx.x;
#pragma unroll
    for (int i = 0; i < RPT; ++i) {
        int r = r0 + i * BLOCK;
        int l = r < nrows ? r : nrows - 1;   // clamp for load; store is guarded
        int ridx = (int)((float)l * rowDelta);
        if (ridx > rowSrcMax) ridx = rowSrcMax;
        p[i]  = srcRows[ridx];
        p2[i] = fmaf(p[i].x, p[i].x, p[i].y * p[i].y);
        m[i]  = __builtin_inff();
    }

    int k = 0;
    for (; k + 4 <= cn; k += 4) {
        float4 q0 = sc[k + 0];
        float4 q1 = sc[k + 1];
        float4 q2 = sc[k + 2];
        float4 q3 = sc[k + 3];
#pragma unroll
        for (int i = 0; i < RPT; ++i) {
            float t;
            t = fmaf(q0.x, p[i].x, q0.z); t = fmaf(q0.y, p[i].y, t); m[i] = fminf(m[i], t);
            t = fmaf(q1.x, p[i].x, q1.z); t = fmaf(q1.y, p[i].y, t); m[i] = fminf(m[i], t);
            t = fmaf(q2.x, p[i].x, q2.z); t = fmaf(q2.y, p[i].y, t); m[i] = fminf(m[i], t);
            t = fmaf(q3.x, p[i].x, q3.z); t = fmaf(q3.y, p[i].y, t); m[i] = fminf(m[i], t);
        }
    }
    for (; k < cn; ++k) {
        float4 q = sc[k];
#pragma unroll
        for (int i = 0; i < RPT; ++i) {
            float t = fmaf(q.x, p[i].x, q.z);
            t = fmaf(q.y, p[i].y, t);
            m[i] = fminf(m[i], t);
        }
    }

#pragma unroll
    for (int i = 0; i < RPT; ++i) {
        int r = r0 + i * BLOCK;
        if (r < nrows) P[by * pstride + r] = m[i] + p2[i];  // partial min of d^2
    }
}

__global__ __launch_bounds__(BLOCK) void reduce_out(const float* __restrict__ ws,
                                                    float* __restrict__ out) {
    const float* P1 = ws;
    const float* P2 = ws + P2_OFF_FLOATS;
    float s = 0.0f;
    for (int t = (int)(blockIdx.x * BLOCK + threadIdx.x); t < NA + NB;
         t += (int)(gridDim.x * BLOCK)) {
        float mn = __builtin_inff();
        if (t < NA) {
#pragma unroll 4
            for (int c = 0; c < NB1Y; ++c) mn = fminf(mn, P1[c * P1_STRIDE + t]);
            s += sqrtf(fmaxf(mn, 0.0f)) * (0.5f / (float)NA);
        } else {
            int r = t - NA;
#pragma unroll 4
            for (int c = 0; c < NB2Y; ++c) mn = fminf(mn, P2[c * P2_STRIDE + r]);
            s += sqrtf(fmaxf(mn, 0.0f)) * (0.5f / (float)NB);
        }
    }
    for (int off = 32; off > 0; off >>= 1) s += __shfl_down(s, off, 64);
    __shared__ float red[4];
    int wave = (int)threadIdx.x >> 6;
    if ((threadIdx.x & 63) == 0) red[wave] = s;
    __syncthreads();
    if (threadIdx.x == 0) {
        float t = red[0] + red[1] + red[2] + red[3];
        atomicAdd(out, t);
    }
}

extern "C" void kernel_launch(void* const* d_in, const int* in_sizes, int n_in,
                              void* d_out, int out_size, void* d_ws, size_t ws_size,
                              hipStream_t stream) {
    (void)in_sizes; (void)n_in; (void)out_size; (void)ws_size;
    const float2* srcA = (const float2*)d_in[0];  // img_render_points (1000*64*2)
    const float2* srcB = (const float2*)d_in[1];  // ref point cloud (80000*2)
    float* ws = (float*)d_ws;
    float* out = (float*)d_out;

    chamfer_partial<<<NBLK1 + NBLK2, BLOCK, 0, stream>>>(srcA, srcB, ws, out);
    reduce_out<<<80, BLOCK, 0, stream>>>(ws, out);
}